// Round 7
// baseline (232.505 us; speedup 1.0000x reference)
//
#include <hip/hip_runtime.h>

// RK4 Gray-Scott, register-pipelined y-march, packed-f32, STATIC circular
// windows (no register shifting). Block = 512 threads = full 1024-wide row
// (2 cols/thread via f2, wrap &511). Vertical neighbors from depth-8
// circular register buffers indexed by compile-time phase (step loop
// unrolled x8); horizontal +-3 via 4-slot rotating LDS row buffers
// (write at t, read at t+3, 1 barrier/step).
// RK sum folded at stage 2: acc = 4*Y1 + 8*Y2 - 4*u0 (row yL-6);
// out = (acc[lag6] + 4*Y3_center + k4) / 12.

typedef float f2 __attribute__((ext_vector_type(2)));

#define HROWS 64
#define NT    512
#define STEPS (HROWS + 24)   // 88 = 11 * 8

#define W0 ((-980.0f / 1e-4f) / 180.0f)
#define W1 ((  270.0f / 1e-4f) / 180.0f)
#define W2 (( -27.0f / 1e-4f) / 180.0f)
#define W3 ((   2.0f / 1e-4f) / 180.0f)

__device__ __forceinline__ f2 sp(float s) { f2 r; r.x = s; r.y = s; return r; }
__device__ __forceinline__ f2 pfma(float s, f2 a, f2 c) {
    return __builtin_elementwise_fma(sp(s), a, c);
}

struct Hq { f2 m2, m1, p1, p2; };   // LDS row at lanes tid-2,tid-1,tid+1,tid+2

__device__ __forceinline__ Hq rdq(const f2* __restrict__ L,
                                  int xm2, int xm1, int xp1, int xp2) {
    Hq q;
    q.m2 = L[xm2]; q.m1 = L[xm1]; q.p1 = L[xp1]; q.p2 = L[xp2];
    return q;
}

// 13-pt Laplacian, packed over 2 cols. w0..w6 = vertical window rows
// (w3 = center); q = horizontal neighbors of the center row.
__device__ __forceinline__ void evalp7(f2 w0, f2 w1, f2 w2, f2 w3, f2 w4,
                                       f2 w5, f2 w6, const Hq& q,
                                       f2& lap, f2& ctr)
{
    ctr = w3;
    f2 vp = pfma(W1, w2 + w4, pfma(W2, w1 + w5, sp(W3) * (w0 + w6)));
    f2 m1 = __builtin_shufflevector(q.m1, ctr, 1, 2);   // {a-1, b-1}
    f2 p1 = __builtin_shufflevector(ctr, q.p1, 1, 2);   // {a+1, b+1}
    f2 m3 = __builtin_shufflevector(q.m2, q.m1, 1, 2);  // {a-3, b-3}
    f2 p3 = __builtin_shufflevector(q.p1, q.p2, 1, 2);  // {a+3, b+3}
    f2 hp = pfma(W1, m1 + p1, pfma(W2, q.m1 + q.p1, sp(W3) * (m3 + p3)));
    lap = pfma(W0, ctr, hp + vp);
}

__global__ __launch_bounds__(NT, 2) void rcnn_rk4_march(
    const float* __restrict__ h,
    const float* __restrict__ pCA, const float* __restrict__ pCB,
    const float* __restrict__ pNA, const float* __restrict__ pNB,
    const float* __restrict__ pf,  const float* __restrict__ pk,
    float* __restrict__ out)
{
    __shared__ f2 Su[4][4][NT], Sv[4][4][NT];   // [stage][slot][col] = 128 KiB

    const int tid = threadIdx.x;
    const int Y0  = blockIdx.x * HROWS;
    const int b   = blockIdx.z;

    const float NA = pNA[0], NB = pNB[0];
    const float ff = pf[0];
    const float kpf = pk[0] + pf[0];
    const float mu_u = 4e-5f / (1.0f + expf(-pCA[0]));
    const float mu_v = 4e-5f / (1.0f + expf(-pCB[0]));

    const size_t baseU = (size_t)b * 2u * 1048576u;
    const size_t baseV = baseU + 1048576u;
    const float* hU = h + baseU + 2 * tid;
    const float* hV = h + baseV + 2 * tid;
    float* oU = out + baseU + 2 * tid;
    float* oV = out + baseV + 2 * tid;

    const int xm2 = (tid - 2) & 511;
    const int xm1 = (tid - 1) & 511;
    const int xp1 = (tid + 1) & 511;
    const int xp2 = (tid + 2) & 511;

    // depth-8 circular register buffers; entry written at step t lives at
    // phase t&7 (in code: compile-time (c+k)&7 since t = tb + c, tb % 8 == 0).
    // Uu/Uv: u0 row yL          (lag j at (c-j)&7)
    // Du/Dv: u0 row yL-5        (u0 lag 5+j)
    // Y1 : Y1 row yL-3 ; Y2 : Y2 row yL-6 ; Y3 : Y3 row yL-9
    // AC : 4*Y1 + 8*Y2 - 4*u0, row yL-6
    f2 Uu[8], Uv[8], Du[8], Dv[8];
    f2 Y1u[8], Y1v[8], Y2u[8], Y2v[8], Y3u[8], Y3v[8];
    f2 ACu[8], ACv[8];

    const f2 z = sp(0.0f);
    #pragma unroll
    for (int j = 0; j < 8; ++j) {
        Uu[j]=z; Uv[j]=z; Du[j]=z; Dv[j]=z;
        Y1u[j]=z; Y1v[j]=z; Y2u[j]=z; Y2v[j]=z; Y3u[j]=z; Y3v[j]=z;
        ACu[j]=z; ACv[j]=z;
    }

    // 2-deep prefetch: pA = even-step rows, pB = odd-step rows
    f2 pAu, pAv, pBu, pBv;
    {
        int r0 = (Y0 - 12) & 1023;
        int r1 = (Y0 - 11) & 1023;
        pAu = *(const f2*)(hU + (size_t)r0 * 1024);
        pAv = *(const f2*)(hV + (size_t)r0 * 1024);
        pBu = *(const f2*)(hU + (size_t)r1 * 1024);
        pBv = *(const f2*)(hV + (size_t)r1 * 1024);
    }

#define STEP(c, G1, G2, G3, G4)                                               \
  {                                                                           \
    const int t_ = tb + (c);                                                  \
    /* early horizontal reads (slots written >=3 steps ago; this step's */    \
    /* writes go to different slots, so no intra-step RAW) */                 \
    Hq q1u, q1v, q2u, q2v, q3u, q3v, q4u, q4v;                                \
    if (G1) { q1u = rdq(&Su[0][((c)+1)&3][0], xm2, xm1, xp1, xp2);            \
              q1v = rdq(&Sv[0][((c)+1)&3][0], xm2, xm1, xp1, xp2); }          \
    if (G2) { q2u = rdq(&Su[1][((c)+2)&3][0], xm2, xm1, xp1, xp2);            \
              q2v = rdq(&Sv[1][((c)+2)&3][0], xm2, xm1, xp1, xp2); }          \
    if (G3) { q3u = rdq(&Su[2][((c)+3)&3][0], xm2, xm1, xp1, xp2);            \
              q3v = rdq(&Sv[2][((c)+3)&3][0], xm2, xm1, xp1, xp2); }          \
    if (G4) { q4u = rdq(&Su[3][(c)&3][0],     xm2, xm1, xp1, xp2);            \
              q4v = rdq(&Sv[3][(c)&3][0],     xm2, xm1, xp1, xp2); }          \
    /* delay copy: u0 lag 5 (written at t-5, phase (c+3)&7) */                \
    Du[(c)&7] = Uu[((c)+3)&7]; Dv[(c)&7] = Uv[((c)+3)&7];                     \
    /* consume prefetch: u0 row yL */                                         \
    f2 cu0 = ((c) & 1) ? pBu : pAu;                                           \
    f2 cv0 = ((c) & 1) ? pBv : pAv;                                           \
    Uu[(c)&7] = cu0; Uv[(c)&7] = cv0;                                         \
    Su[0][(c)&3][tid] = cu0; Sv[0][(c)&3][tid] = cv0;                         \
    /* issue prefetch for row yL+2 */                                         \
    {                                                                         \
      int yn = (Y0 - 10 + t_) & 1023;                                         \
      f2 au = *(const f2*)(hU + (size_t)yn * 1024);                           \
      f2 av = *(const f2*)(hV + (size_t)yn * 1024);                           \
      if ((c) & 1) { pBu = au; pBv = av; } else { pAu = au; pAv = av; }       \
    }                                                                         \
    if (G1) { /* k1 on u0, row yL-3 */                                        \
      f2 lU, cU, lV, cV;                                                      \
      evalp7(Uu[((c)+2)&7], Uu[((c)+3)&7], Uu[((c)+4)&7], Uu[((c)+5)&7],      \
             Uu[((c)+6)&7], Uu[((c)+7)&7], Uu[(c)&7], q1u, lU, cU);           \
      evalp7(Uv[((c)+2)&7], Uv[((c)+3)&7], Uv[((c)+4)&7], Uv[((c)+5)&7],      \
             Uv[((c)+6)&7], Uv[((c)+7)&7], Uv[(c)&7], q1v, lV, cV);           \
      f2 uv2 = cU * cV * cV;                                                  \
      f2 kU = pfma(mu_u, lU, pfma(NA, uv2, pfma(-ff, cU, sp(ff))));           \
      f2 kV = pfma(mu_v, lV, pfma(NB, uv2, sp(-kpf) * cV));                   \
      f2 nu = pfma(0.25f, kU, cU), nv = pfma(0.25f, kV, cV);                  \
      Y1u[(c)&7] = nu; Y1v[(c)&7] = nv;                                       \
      Su[1][((c)+1)&3][tid] = nu; Sv[1][((c)+1)&3][tid] = nv;                 \
    }                                                                         \
    if (G2) { /* k2 on Y1, row yL-6 */                                        \
      f2 lU, cU, lV, cV;                                                      \
      evalp7(Y1u[((c)+2)&7], Y1u[((c)+3)&7], Y1u[((c)+4)&7], Y1u[((c)+5)&7],  \
             Y1u[((c)+6)&7], Y1u[((c)+7)&7], Y1u[(c)&7], q2u, lU, cU);        \
      evalp7(Y1v[((c)+2)&7], Y1v[((c)+3)&7], Y1v[((c)+4)&7], Y1v[((c)+5)&7],  \
             Y1v[((c)+6)&7], Y1v[((c)+7)&7], Y1v[(c)&7], q2v, lV, cV);        \
      f2 uv2 = cU * cV * cV;                                                  \
      f2 kU = pfma(mu_u, lU, pfma(NA, uv2, pfma(-ff, cU, sp(ff))));           \
      f2 kV = pfma(mu_v, lV, pfma(NB, uv2, sp(-kpf) * cV));                   \
      f2 bu = Du[((c)+7)&7], bv = Dv[((c)+7)&7];        /* u0 lag 6 */        \
      f2 nu = pfma(0.25f, kU, bu), nv = pfma(0.25f, kV, bv);                  \
      Y2u[(c)&7] = nu; Y2v[(c)&7] = nv;                                       \
      Su[2][((c)+2)&3][tid] = nu; Sv[2][((c)+2)&3][tid] = nv;                 \
      f2 aU = pfma(4.0f, Y1u[((c)+5)&7], sp(8.0f) * nu);                      \
      f2 aV = pfma(4.0f, Y1v[((c)+5)&7], sp(8.0f) * nv);                      \
      ACu[(c)&7] = pfma(-4.0f, bu, aU);                                       \
      ACv[(c)&7] = pfma(-4.0f, bv, aV);                                       \
    }                                                                         \
    if (G3) { /* k3 on Y2, row yL-9 */                                        \
      f2 lU, cU, lV, cV;                                                      \
      evalp7(Y2u[((c)+2)&7], Y2u[((c)+3)&7], Y2u[((c)+4)&7], Y2u[((c)+5)&7],  \
             Y2u[((c)+6)&7], Y2u[((c)+7)&7], Y2u[(c)&7], q3u, lU, cU);        \
      evalp7(Y2v[((c)+2)&7], Y2v[((c)+3)&7], Y2v[((c)+4)&7], Y2v[((c)+5)&7],  \
             Y2v[((c)+6)&7], Y2v[((c)+7)&7], Y2v[(c)&7], q3v, lV, cV);        \
      f2 uv2 = cU * cV * cV;                                                  \
      f2 kU = pfma(mu_u, lU, pfma(NA, uv2, pfma(-ff, cU, sp(ff))));           \
      f2 kV = pfma(mu_v, lV, pfma(NB, uv2, sp(-kpf) * cV));                   \
      f2 nu = pfma(0.5f, kU, Du[((c)+4)&7]);             /* u0 lag 9 */       \
      f2 nv = pfma(0.5f, kV, Dv[((c)+4)&7]);                                  \
      Y3u[(c)&7] = nu; Y3v[(c)&7] = nv;                                       \
      Su[3][((c)+3)&3][tid] = nu; Sv[3][((c)+3)&3][tid] = nv;                 \
    }                                                                         \
    if (G4) { /* k4 on Y3, row yL-12 ; write output */                        \
      f2 lU, cU, lV, cV;                                                      \
      evalp7(Y3u[((c)+2)&7], Y3u[((c)+3)&7], Y3u[((c)+4)&7], Y3u[((c)+5)&7],  \
             Y3u[((c)+6)&7], Y3u[((c)+7)&7], Y3u[(c)&7], q4u, lU, cU);        \
      evalp7(Y3v[((c)+2)&7], Y3v[((c)+3)&7], Y3v[((c)+4)&7], Y3v[((c)+5)&7],  \
             Y3v[((c)+6)&7], Y3v[((c)+7)&7], Y3v[(c)&7], q4v, lV, cV);        \
      f2 uv2 = cU * cV * cV;                                                  \
      f2 kU = pfma(mu_u, lU, pfma(NA, uv2, pfma(-ff, cU, sp(ff))));           \
      f2 kV = pfma(mu_v, lV, pfma(NB, uv2, sp(-kpf) * cV));                   \
      f2 sU = pfma(4.0f, cU, kU) + ACu[((c)+2)&7];       /* acc lag 6 */      \
      f2 sV = pfma(4.0f, cV, kV) + ACv[((c)+2)&7];                            \
      f2 oUq = sp(1.0f / 12.0f) * sU;                                         \
      f2 oVq = sp(1.0f / 12.0f) * sV;                                         \
      int yS = Y0 + t_ - 24;                                                  \
      *(f2*)(oU + (size_t)yS * 1024) = oUq;                                   \
      *(f2*)(oV + (size_t)yS * 1024) = oVq;                                   \
    }                                                                         \
    asm volatile("s_waitcnt lgkmcnt(0)" ::: "memory");                        \
    __builtin_amdgcn_s_barrier();                                             \
  }

#define STEP_W(c) STEP(c, t_ >= 6, t_ >= 12, t_ >= 18, t_ >= 24)
#define STEP_H(c) STEP(c, 1, 1, 1, 1)

    int tb = 0;
    for (; tb < 24; tb += 8) {          // warmup: runtime guards
        STEP_W(0) STEP_W(1) STEP_W(2) STEP_W(3)
        STEP_W(4) STEP_W(5) STEP_W(6) STEP_W(7)
    }
    for (; tb < STEPS; tb += 8) {       // hot: straight-line
        STEP_H(0) STEP_H(1) STEP_H(2) STEP_H(3)
        STEP_H(4) STEP_H(5) STEP_H(6) STEP_H(7)
    }
#undef STEP_W
#undef STEP_H
#undef STEP
}

extern "C" void kernel_launch(void* const* d_in, const int* in_sizes, int n_in,
                              void* d_out, int out_size, void* d_ws, size_t ws_size,
                              hipStream_t stream) {
    const float* h   = (const float*)d_in[0];
    const float* pCA = (const float*)d_in[1];
    const float* pCB = (const float*)d_in[2];
    const float* pNA = (const float*)d_in[3];
    const float* pNB = (const float*)d_in[4];
    const float* pf  = (const float*)d_in[5];
    const float* pk  = (const float*)d_in[6];
    float* outp = (float*)d_out;

    dim3 grid(1024 / HROWS, 1, 16);   // 16 strips x 16 batches = 256 blocks
    dim3 block(NT);
    rcnn_rk4_march<<<grid, block, 0, stream>>>(h, pCA, pCB, pNA, pNB, pf, pk, outp);
}

// Round 8
// 122.647 us; speedup vs baseline: 1.8957x; 1.8957x over previous
//
#include <hip/hip_runtime.h>

// RK4 Gray-Scott, register-pipelined y-march, packed-f32.
// Block = 512 threads = full 1024-wide row (2 cols/thread via f2, wrap &511).
// Vertical neighbors from per-thread shift-register windows; horizontal +-3:
//   - stage 1 (u0): re-read from GLOBAL (row is L2-resident; vmem pipe is idle)
//   - stages 2-4 (Y1,Y2,Y3): 4-slot rotating LDS row buffers
//     (write at t, read at t+3, 1 barrier/step). LDS = 96 KiB.
// RK sum reconstructed from Y windows: out = u0 + (1/12)(4Y1+8Y2+4Y3-16u0+k4).

typedef float f2 __attribute__((ext_vector_type(2)));

#define HROWS 64
#define NT    512
#define STEPS (HROWS + 24)

#define W0 ((-980.0f / 1e-4f) / 180.0f)
#define W1 ((  270.0f / 1e-4f) / 180.0f)
#define W2 (( -27.0f / 1e-4f) / 180.0f)
#define W3 ((   2.0f / 1e-4f) / 180.0f)

__device__ __forceinline__ f2 sp(float s) { f2 r; r.x = s; r.y = s; return r; }
__device__ __forceinline__ f2 pfma(float s, f2 a, f2 c) {
    return __builtin_elementwise_fma(sp(s), a, c);
}

struct Hq { f2 m2, m1, p1, p2; };   // row values at f2 indices tid-2,tid-1,tid+1,tid+2

__device__ __forceinline__ Hq rdq(const f2* __restrict__ L,
                                  int xm2, int xm1, int xp1, int xp2) {
    Hq q;
    q.m2 = L[xm2]; q.m1 = L[xm1]; q.p1 = L[xp1]; q.p2 = L[xp2];
    return q;
}

// 13-pt Laplacian, packed over 2 cols. w = 7-row vertical window (center w[3]).
__device__ __forceinline__ void evalp(const f2* __restrict__ w, const Hq& q,
                                      f2& lap, f2& ctr)
{
    ctr = w[3];
    f2 vp = pfma(W1, w[2] + w[4], pfma(W2, w[1] + w[5], sp(W3) * (w[0] + w[6])));
    f2 m1 = __builtin_shufflevector(q.m1, ctr, 1, 2);   // {a-1, b-1}
    f2 p1 = __builtin_shufflevector(ctr, q.p1, 1, 2);   // {a+1, b+1}
    f2 m3 = __builtin_shufflevector(q.m2, q.m1, 1, 2);  // {a-3, b-3}
    f2 p3 = __builtin_shufflevector(q.p1, q.p2, 1, 2);  // {a+3, b+3}
    f2 hp = pfma(W1, m1 + p1, pfma(W2, q.m1 + q.p1, sp(W3) * (m3 + p3)));
    lap = pfma(W0, ctr, hp + vp);
}

#define SH6(A)  { A[5]=A[4]; A[4]=A[3]; A[3]=A[2]; A[2]=A[1]; A[1]=A[0]; }
#define SH7(A)  { A[6]=A[5]; A[5]=A[4]; A[4]=A[3]; A[3]=A[2]; A[2]=A[1]; A[1]=A[0]; }
#define SH10(A) { A[9]=A[8]; A[8]=A[7]; A[7]=A[6]; A[6]=A[5]; A[5]=A[4]; A[4]=A[3]; A[3]=A[2]; A[2]=A[1]; A[1]=A[0]; }

__global__ __launch_bounds__(NT, 2) void rcnn_rk4_march(
    const float* __restrict__ h,
    const float* __restrict__ pCA, const float* __restrict__ pCB,
    const float* __restrict__ pNA, const float* __restrict__ pNB,
    const float* __restrict__ pf,  const float* __restrict__ pk,
    float* __restrict__ out)
{
    __shared__ f2 Su[3][4][NT], Sv[3][4][NT];   // [Y1,Y2,Y3][slot][col] = 96 KiB

    const int tid = threadIdx.x;
    const int Y0  = blockIdx.x * HROWS;
    const int b   = blockIdx.z;

    const float NA = pNA[0], NB = pNB[0];
    const float ff = pf[0];
    const float kpf = pk[0] + pf[0];
    const float mu_u = 4e-5f / (1.0f + expf(-pCA[0]));
    const float mu_v = 4e-5f / (1.0f + expf(-pCB[0]));

    const size_t baseU = (size_t)b * 2u * 1048576u;
    const size_t baseV = baseU + 1048576u;
    const float* hU  = h + baseU;          // row base (for neighbor re-reads)
    const float* hV  = h + baseV;
    const float* hUc = hU + 2 * tid;       // own columns
    const float* hVc = hV + 2 * tid;
    float* oU = out + baseU + 2 * tid;
    float* oV = out + baseV + 2 * tid;

    const int xm2 = (tid - 2) & 511;
    const int xm1 = (tid - 1) & 511;
    const int xp1 = (tid + 1) & 511;
    const int xp2 = (tid + 2) & 511;

    // shift windows (post-shift at step t, yL = Y0-12+t):
    f2 u0u[7], u0v[7];     // u0 rows yL-j
    f2 du[6],  dv[6];      // u0 rows yL-7-j
    f2 y1u[10], y1v[10];   // Y1 rows yL-3-j
    f2 y2u[7],  y2v[7];    // Y2 rows yL-6-j
    f2 y3u[7],  y3v[7];    // Y3 rows yL-9-j

    const f2 z = sp(0.0f);
    #pragma unroll
    for (int j = 0; j < 7; ++j) { u0u[j]=z; u0v[j]=z; y2u[j]=z; y2v[j]=z; y3u[j]=z; y3v[j]=z; }
    #pragma unroll
    for (int j = 0; j < 6; ++j) { du[j]=z; dv[j]=z; }
    #pragma unroll
    for (int j = 0; j < 10; ++j) { y1u[j]=z; y1v[j]=z; }

    // 1-deep prefetch of own columns, row Y0-12
    f2 pu, pv;
    {
        int yl = (Y0 - 12) & 1023;
        pu = *(const f2*)(hUc + (size_t)yl * 1024);
        pv = *(const f2*)(hVc + (size_t)yl * 1024);
    }

#define STEP(D1, D2, D3, D4, tt)                                              \
  {                                                                           \
    const int t_ = (tt);                                                      \
    /* stage-1 horizontal neighbors from GLOBAL: u0 row yL-3 (L2-resident) */ \
    Hq q1u, q1v;                                                              \
    if (D1) {                                                                 \
      int ym3 = (Y0 - 15 + t_) & 1023;                                        \
      const float* rU = hU + (size_t)ym3 * 1024;                              \
      const float* rV = hV + (size_t)ym3 * 1024;                              \
      q1u.m2 = *(const f2*)(rU + 2 * xm2); q1u.m1 = *(const f2*)(rU + 2 * xm1); \
      q1u.p1 = *(const f2*)(rU + 2 * xp1); q1u.p2 = *(const f2*)(rU + 2 * xp2); \
      q1v.m2 = *(const f2*)(rV + 2 * xm2); q1v.m1 = *(const f2*)(rV + 2 * xm1); \
      q1v.p1 = *(const f2*)(rV + 2 * xp1); q1v.p2 = *(const f2*)(rV + 2 * xp2); \
    }                                                                         \
    /* consume prefetch: u0 row yL */                                         \
    SH6(du); SH6(dv); du[0] = u0u[6]; dv[0] = u0v[6];                         \
    SH7(u0u); SH7(u0v); u0u[0] = pu; u0v[0] = pv;                             \
    /* issue prefetch for row yL+1 */                                         \
    {                                                                         \
      int yn = (Y0 - 11 + t_) & 1023;                                         \
      pu = *(const f2*)(hUc + (size_t)yn * 1024);                             \
      pv = *(const f2*)(hVc + (size_t)yn * 1024);                             \
    }                                                                         \
    if (D1) { /* k1 on u0, row yL-3 */                                        \
      f2 lU, cU, lV, cV;                                                      \
      evalp(u0u, q1u, lU, cU);                                                \
      evalp(u0v, q1v, lV, cV);                                                \
      f2 uv2 = cU * cV * cV;                                                  \
      f2 kU = pfma(mu_u, lU, pfma(NA, uv2, pfma(-ff, cU, sp(ff))));           \
      f2 kV = pfma(mu_v, lV, pfma(NB, uv2, sp(-kpf) * cV));                   \
      f2 nu = pfma(0.25f, kU, cU), nv = pfma(0.25f, kV, cV);                  \
      SH10(y1u); SH10(y1v); y1u[0] = nu; y1v[0] = nv;                         \
      Su[0][(t_ + 1) & 3][tid] = nu; Sv[0][(t_ + 1) & 3][tid] = nv;           \
    }                                                                         \
    if (D2) { /* k2 on Y1, row yL-6 */                                        \
      Hq q2u = rdq(&Su[0][(t_ + 2) & 3][0], xm2, xm1, xp1, xp2);              \
      Hq q2v = rdq(&Sv[0][(t_ + 2) & 3][0], xm2, xm1, xp1, xp2);              \
      f2 lU, cU, lV, cV;                                                      \
      evalp(y1u, q2u, lU, cU);                                                \
      evalp(y1v, q2v, lV, cV);                                                \
      f2 uv2 = cU * cV * cV;                                                  \
      f2 kU = pfma(mu_u, lU, pfma(NA, uv2, pfma(-ff, cU, sp(ff))));           \
      f2 kV = pfma(mu_v, lV, pfma(NB, uv2, sp(-kpf) * cV));                   \
      f2 nu = pfma(0.25f, kU, u0u[6]), nv = pfma(0.25f, kV, u0v[6]);          \
      SH7(y2u); SH7(y2v); y2u[0] = nu; y2v[0] = nv;                           \
      Su[1][(t_ + 2) & 3][tid] = nu; Sv[1][(t_ + 2) & 3][tid] = nv;           \
    }                                                                         \
    if (D3) { /* k3 on Y2, row yL-9 */                                        \
      Hq q3u = rdq(&Su[1][(t_ + 3) & 3][0], xm2, xm1, xp1, xp2);              \
      Hq q3v = rdq(&Sv[1][(t_ + 3) & 3][0], xm2, xm1, xp1, xp2);              \
      f2 lU, cU, lV, cV;                                                      \
      evalp(y2u, q3u, lU, cU);                                                \
      evalp(y2v, q3v, lV, cV);                                                \
      f2 uv2 = cU * cV * cV;                                                  \
      f2 kU = pfma(mu_u, lU, pfma(NA, uv2, pfma(-ff, cU, sp(ff))));           \
      f2 kV = pfma(mu_v, lV, pfma(NB, uv2, sp(-kpf) * cV));                   \
      f2 nu = pfma(0.5f, kU, du[2]), nv = pfma(0.5f, kV, dv[2]);              \
      SH7(y3u); SH7(y3v); y3u[0] = nu; y3v[0] = nv;                           \
      Su[2][(t_ + 3) & 3][tid] = nu; Sv[2][(t_ + 3) & 3][tid] = nv;           \
    }                                                                         \
    if (D4) { /* k4 on Y3, row yL-12 ; write output */                        \
      Hq q4u = rdq(&Su[2][t_ & 3][0], xm2, xm1, xp1, xp2);                    \
      Hq q4v = rdq(&Sv[2][t_ & 3][0], xm2, xm1, xp1, xp2);                    \
      f2 lU, cU4, lV, cV4;                                                    \
      evalp(y3u, q4u, lU, cU4);                                               \
      evalp(y3v, q4v, lV, cV4);                                               \
      f2 uv2 = cU4 * cV4 * cV4;                                               \
      f2 kU = pfma(mu_u, lU, pfma(NA, uv2, pfma(-ff, cU4, sp(ff))));          \
      f2 kV = pfma(mu_v, lV, pfma(NB, uv2, sp(-kpf) * cV4));                  \
      f2 aU = pfma(4.0f, y1u[9], kU);                                         \
      aU = pfma(8.0f, y2u[6], aU);                                            \
      aU = pfma(4.0f, cU4, aU);                                               \
      aU = pfma(-16.0f, du[5], aU);                                           \
      f2 aV = pfma(4.0f, y1v[9], kV);                                         \
      aV = pfma(8.0f, y2v[6], aV);                                            \
      aV = pfma(4.0f, cV4, aV);                                               \
      aV = pfma(-16.0f, dv[5], aV);                                           \
      f2 oUq = pfma(1.0f / 12.0f, aU, du[5]);                                 \
      f2 oVq = pfma(1.0f / 12.0f, aV, dv[5]);                                 \
      int yS = Y0 + t_ - 24;                                                  \
      *(f2*)(oU + (size_t)yS * 1024) = oUq;                                   \
      *(f2*)(oV + (size_t)yS * 1024) = oVq;                                   \
    }                                                                         \
    asm volatile("s_waitcnt lgkmcnt(0)" ::: "memory");                        \
    __builtin_amdgcn_s_barrier();                                             \
  }

    int t = 0;
    #pragma unroll 2
    for (; t < 6;  ++t) STEP(0, 0, 0, 0, t)
    #pragma unroll 2
    for (; t < 12; ++t) STEP(1, 0, 0, 0, t)
    #pragma unroll 2
    for (; t < 18; ++t) STEP(1, 1, 0, 0, t)
    #pragma unroll 2
    for (; t < 24; ++t) STEP(1, 1, 1, 0, t)
    #pragma unroll 4
    for (; t < STEPS; ++t) STEP(1, 1, 1, 1, t)
#undef STEP
}

extern "C" void kernel_launch(void* const* d_in, const int* in_sizes, int n_in,
                              void* d_out, int out_size, void* d_ws, size_t ws_size,
                              hipStream_t stream) {
    const float* h   = (const float*)d_in[0];
    const float* pCA = (const float*)d_in[1];
    const float* pCB = (const float*)d_in[2];
    const float* pNA = (const float*)d_in[3];
    const float* pNB = (const float*)d_in[4];
    const float* pf  = (const float*)d_in[5];
    const float* pk  = (const float*)d_in[6];
    float* outp = (float*)d_out;

    dim3 grid(1024 / HROWS, 1, 16);   // 16 strips x 16 batches = 256 blocks
    dim3 block(NT);
    rcnn_rk4_march<<<grid, block, 0, stream>>>(h, pCA, pCB, pNA, pNB, pf, pk, outp);
}